// Round 5
// baseline (152.092 us; speedup 1.0000x reference)
//
#include <hip/hip_runtime.h>

#define POPN   4096
#define LENN   2048
#define GRIDN  512
#define NCODE  (GRIDN * GRIDN)     // 262144
#define TPB    512
#define PPB    8                   // paths per block; wave w owns path w
#define NBLK   (POPN / PPB)        // 512 blocks
#define NCHUNK 64
#define CHUNK_F 4096               // floats per tp chunk (16 KB)
#define BINCAP 352                 // mean 256, +6 sigma
#define OVCAP  512

__global__ __launch_bounds__(TPB) void fitness_kernel(
    const float* __restrict__ pop,
    const float* __restrict__ tp,
    float* __restrict__ out)
{
    // 45056 B; doubles as the 32 KB dup bitmap during phase C (C precedes B)
    __shared__ unsigned short bins[NCHUNK][BINCAP];
    __shared__ unsigned bincnt[NCHUNK];
    __shared__ float    chunk[CHUNK_F];   // 16 KB staged tp chunk
    __shared__ unsigned ovlist[OVCAP];    // dup-list in C, bin-overflow in B/D
    __shared__ unsigned ovcnt;
    __shared__ float    partial[PPB][8];  // per-path reward partials

    const int tid  = threadIdx.x;
    const int w    = tid >> 6;            // wave index = path-in-block
    const int lane = tid & 63;
    const int blk  = blockIdx.x;

    if (tid < NCHUNK) bincnt[tid] = 0u;
    if (tid < PPB * 8) ((float*)partial)[tid] = 0.0f;

    // ---- Phase A: load points (coalesced), codes -> regs, continuity ----
    const float* p = pop + ((size_t)(blk * PPB + w)) * (LENN * 2);
    int codeA[16], codeB[16];             // statically indexed via full unroll
    int cont = 0;
    float carryx = 0.0f, carryy = 0.0f;
    #pragma unroll 16
    for (int j = 0; j < 16; ++j) {
        // points 2*lane+128j and 2*lane+1+128j: 1KB contiguous per wave-instr
        float4 f = ((const float4*)p)[lane + 64 * j];
        codeA[j] = (int)f.x * GRIDN + (int)f.y;
        codeB[j] = (int)f.z * GRIDN + (int)f.w;
        float ppx = __shfl_up(f.z, 1, 64);     // prev pair's 2nd point
        float ppy = __shfl_up(f.w, 1, 64);
        if (lane == 0) { ppx = carryx; ppy = carryy; }
        if (!(j == 0 && lane == 0)) {          // no incoming step for point 0
            if (fabsf(f.x - ppx) + fabsf(f.y - ppy) > 1.0f) cont++;
        }
        if (fabsf(f.z - f.x) + fabsf(f.w - f.y) > 1.0f) cont++;
        carryx = __shfl(f.z, 63, 64);          // lane63's 2nd point -> next j
        carryy = __shfl(f.w, 63, 64);
    }
    #pragma unroll
    for (int off = 32; off > 0; off >>= 1) cont += __shfl_down(cont, off, 64);
    // lane0 of each wave now holds its path's continuity count

    // ---- Phase C: per-path duplicate count (bitmap aliases bins region) ----
    unsigned* bitmap = (unsigned*)bins;        // 8192 u32 = 32 KB <= 44 KB
    int dupc = 0;
    for (int pp = 0; pp < PPB; ++pp) {
        uint4 z4 = make_uint4(0u, 0u, 0u, 0u);
        for (int i = tid; i < 2048; i += TPB) ((uint4*)bitmap)[i] = z4;
        if (tid == 0) ovcnt = 0u;
        __syncthreads();
        if (w == pp) {
            #pragma unroll 16
            for (int j = 0; j < 16; ++j) {
                int c0 = codeA[j];
                unsigned b0 = 1u << (c0 & 31);
                unsigned o0 = atomicOr(&bitmap[(unsigned)c0 >> 5], b0);
                if (o0 & b0) { unsigned ix = atomicAdd(&ovcnt, 1u); if (ix < OVCAP) ovlist[ix] = (unsigned)c0; }
                int c1 = codeB[j];
                unsigned b1 = 1u << (c1 & 31);
                unsigned o1 = atomicOr(&bitmap[(unsigned)c1 >> 5], b1);
                if (o1 & b1) { unsigned ix = atomicAdd(&ovcnt, 1u); if (ix < OVCAP) ovlist[ix] = (unsigned)c1; }
            }
        }
        __syncthreads();
        if (w == pp) {
            int k = (int)ovcnt; if (k > OVCAP) k = OVCAP;
            int myfirst = 0;
            for (int i = lane; i < k; i += 64) {   // k ~ 8 expected
                unsigned c = ovlist[i];
                bool f1 = true;
                for (int j2 = 0; j2 < i; ++j2)
                    if (ovlist[j2] == c) { f1 = false; break; }
                if (f1) myfirst++;
            }
            #pragma unroll
            for (int off = 32; off > 0; off >>= 1) myfirst += __shfl_down(myfirst, off, 64);
            dupc = myfirst;                        // lane0 valid
        }
        __syncthreads();                           // list reads done before next reset
    }

    // ---- Phase B: bin all codes by 16KB table chunk ----
    if (tid == 0) ovcnt = 0u;
    __syncthreads();
    #pragma unroll 16
    for (int j = 0; j < 16; ++j) {
        int c0 = codeA[j];
        unsigned b0 = (unsigned)c0 >> 12;
        unsigned i0 = atomicAdd(&bincnt[b0], 1u);
        if (i0 < BINCAP) bins[b0][i0] = (unsigned short)((w << 12) | (c0 & 4095));
        else { unsigned ox = atomicAdd(&ovcnt, 1u); if (ox < OVCAP) ovlist[ox] = ((unsigned)w << 18) | (unsigned)c0; }
        int c1 = codeB[j];
        unsigned b1 = (unsigned)c1 >> 12;
        unsigned i1 = atomicAdd(&bincnt[b1], 1u);
        if (i1 < BINCAP) bins[b1][i1] = (unsigned short)((w << 12) | (c1 & 4095));
        else { unsigned ox = atomicAdd(&ovcnt, 1u); if (ox < OVCAP) ovlist[ox] = ((unsigned)w << 18) | (unsigned)c1; }
    }
    __syncthreads();

    // ---- Phase D: 64 sequential chunk passes; T14 reg-prefetch staging ----
    float4 r0, r1;
    {
        const float4* src = (const float4*)tp;
        r0 = src[tid * 2];
        r1 = src[tid * 2 + 1];
    }
    for (int c = 0; c < NCHUNK; ++c) {
        ((float4*)chunk)[tid * 2]     = r0;        // floats [8t, 8t+8)
        ((float4*)chunk)[tid * 2 + 1] = r1;
        if (c + 1 < NCHUNK) {                      // issue next chunk's loads now;
            const float4* src = (const float4*)(tp + (size_t)(c + 1) * CHUNK_F);
            r0 = src[tid * 2];                     // latency hides under process
            r1 = src[tid * 2 + 1];
        }
        __syncthreads();
        int n = (int)bincnt[c]; if (n > BINCAP) n = BINCAP;
        for (int i = tid; i < n; i += TPB) {
            unsigned e = bins[c][i];
            atomicAdd(&partial[e >> 12][tid & 7], chunk[e & 4095]);
        }
        __syncthreads();
    }

    // bin-overflow entries (expected 0): direct L2 gather
    {
        int no = (int)ovcnt; if (no > OVCAP) no = OVCAP;
        for (int i = tid; i < no; i += TPB) {
            unsigned u = ovlist[i];
            atomicAdd(&partial[u >> 18][tid & 7], tp[u & (NCODE - 1)]);
        }
    }
    __syncthreads();

    // ---- Epilogue: per-wave reduce + fitness ----
    float s = (lane < 8) ? partial[w][lane] : 0.0f;
    s += __shfl_down(s, 4, 64);
    s += __shfl_down(s, 2, 64);
    s += __shfl_down(s, 1, 64);
    if (lane == 0)
        out[blk * PPB + w] = s - 0.5f * (float)cont - 0.2f * (float)dupc;
}

extern "C" void kernel_launch(void* const* d_in, const int* in_sizes, int n_in,
                              void* d_out, int out_size, void* d_ws, size_t ws_size,
                              hipStream_t stream) {
    const float* pop = (const float*)d_in[0];   // [POP, LEN, 2] f32
    const float* tp  = (const float*)d_in[1];   // [GRID, GRID] f32
    float* out = (float*)d_out;                 // [POP] f32
    (void)in_sizes; (void)n_in; (void)out_size; (void)d_ws; (void)ws_size;

    fitness_kernel<<<NBLK, TPB, 0, stream>>>(pop, tp, out);
}

// Round 6
// 53.538 us; speedup vs baseline: 2.8409x; 2.8409x over previous
//
#include <hip/hip_runtime.h>

#define POPN  4096
#define LENN  2048
#define GRIDN 512
#define TPB   256
#define NSLOT 4096      // hash slots = 16 KB; 2048 codes -> 50% load factor
#define LCAP  896       // dup-overflow list (3.5 KB); LDS total < 20 KB -> 8 blocks/CU

__global__ __launch_bounds__(TPB) void fitness_kernel(
    const float* __restrict__ pop,
    const float* __restrict__ tp,
    float* __restrict__ out)
{
    __shared__ unsigned tab[NSLOT];   // 0 = empty, else code+1
    __shared__ unsigned list[LCAP];   // one entry per 2nd+ visit
    __shared__ unsigned lcount;
    __shared__ float    wred[TPB / 64];

    const int tid  = threadIdx.x;
    const int path = blockIdx.x;

    // Zero hash table: 4096 u32 / 256 thr = 4 uint4 stores each.
    {
        uint4 z = make_uint4(0u, 0u, 0u, 0u);
        #pragma unroll
        for (int i = 0; i < NSLOT / 4 / TPB; ++i)
            ((uint4*)tab)[tid + i * TPB] = z;
        if (tid == 0) lcount = 0u;
    }

    // Thread t owns points [8t, 8t+8): four float4 loads (coalesced).
    const float*  p  = pop + (size_t)path * (LENN * 2);
    const float4* p4 = (const float4*)p;
    float x[9], y[9];
    #pragma unroll
    for (int j = 0; j < 4; ++j) {
        float4 f = p4[tid * 4 + j];
        x[2 * j]     = f.x; y[2 * j]     = f.y;
        x[2 * j + 1] = f.z; y[2 * j + 1] = f.w;
    }
    // Seam point 8t+8: neighbor lane's first point; lane 63 of each wave loads.
    {
        float nx = __shfl_down(x[0], 1, 64);
        float ny = __shfl_down(y[0], 1, 64);
        if ((tid & 63) == 63 && tid * 8 + 8 < LENN) {
            float2 c = ((const float2*)p)[tid * 8 + 8];
            nx = c.x; ny = c.y;
        }
        x[8] = nx; y[8] = ny;
    }
    const int nsteps = (tid * 8 + 8 < LENN) ? 8 : 7;

    int code[8];
    #pragma unroll
    for (int j = 0; j < 8; ++j)
        code[j] = (int)x[j] * GRIDN + (int)y[j];

    // 8 independent random gathers into the L2-resident 1MB table.
    float g[8];
    #pragma unroll
    for (int j = 0; j < 8; ++j) g[j] = tp[code[j]];

    __syncthreads();                 // hash table zeroed

    // Exact dup detection via open-addressing hash (linear probe).
    #pragma unroll
    for (int j = 0; j < 8; ++j) {
        unsigned v = (unsigned)code[j] + 1u;
        unsigned s = ((unsigned)code[j] * 2654435761u) >> 20;   // 12-bit slot
        for (;;) {
            unsigned old = atomicCAS(&tab[s], 0u, v);
            if (old == 0u) break;                 // first visit: inserted
            if (old == v) {                       // 2nd+ visit: record
                unsigned ix = atomicAdd(&lcount, 1u);
                if (ix < LCAP) list[ix] = v;
                break;
            }
            s = (s + 1) & (NSLOT - 1);            // other code: probe next
        }
    }

    int cont = 0;
    #pragma unroll
    for (int j = 0; j < 8; ++j)
        if (j < nsteps && fabsf(x[j + 1] - x[j]) + fabsf(y[j + 1] - y[j]) > 1.0f)
            cont++;

    float reward = ((g[0] + g[1]) + (g[2] + g[3])) + ((g[4] + g[5]) + (g[6] + g[7]));

    __syncthreads();                 // list + lcount complete

    // n_dup_positions = unique codes in list (k ~ 8 for this data).
    int k = (int)lcount; if (k > LCAP) k = LCAP;
    int dupc = 0;
    for (int i = tid; i < k; i += TPB) {
        unsigned c = list[i];
        bool first = true;
        for (int j2 = 0; j2 < i; ++j2)
            if (list[j2] == c) { first = false; break; }
        if (first) dupc++;
    }

    float fit = reward - 0.5f * (float)cont - 0.2f * (float)dupc;

    // Wave shuffle reduce + cross-wave combine.
    #pragma unroll
    for (int off = 32; off > 0; off >>= 1)
        fit += __shfl_down(fit, off, 64);
    if ((tid & 63) == 0) wred[tid >> 6] = fit;
    __syncthreads();
    if (tid == 0)
        out[path] = (wred[0] + wred[1]) + (wred[2] + wred[3]);
}

extern "C" void kernel_launch(void* const* d_in, const int* in_sizes, int n_in,
                              void* d_out, int out_size, void* d_ws, size_t ws_size,
                              hipStream_t stream) {
    const float* pop = (const float*)d_in[0];   // [POP, LEN, 2] f32
    const float* tp  = (const float*)d_in[1];   // [GRID, GRID] f32
    float* out = (float*)d_out;                 // [POP] f32
    (void)in_sizes; (void)n_in; (void)out_size; (void)d_ws; (void)ws_size;

    fitness_kernel<<<POPN, TPB, 0, stream>>>(pop, tp, out);
}

// Round 7
// 43.974 us; speedup vs baseline: 3.4587x; 1.2175x over previous
//
#include <hip/hip_runtime.h>

#define POPN  4096
#define LENN  2048
#define GRIDN 512
#define NWORDS (GRIDN * GRIDN / 32)   // 8192 u32 seen-bitmap (32 KB)
#define TPB   512
#define LCAP  2047                    // worst-case extras; LDS total = 40960 B -> 4 blocks/CU

__global__ __launch_bounds__(TPB) void fitness_kernel(
    const float* __restrict__ pop,
    const float* __restrict__ tp,
    float* __restrict__ out)
{
    __shared__ unsigned seen[NWORDS];   // bit set -> code visited at least once
    __shared__ unsigned lcount;
    __shared__ unsigned list[LCAP];     // one entry per extra (2nd+) visit

    const int tid  = threadIdx.x;
    const int path = blockIdx.x;

    // Zero seen bitmap (16B LDS stores) + counter.
    {
        uint4 z = make_uint4(0u, 0u, 0u, 0u);
        uint4* s4 = (uint4*)seen;
        #pragma unroll
        for (int i = tid; i < NWORDS / 4; i += TPB) s4[i] = z;
        if (tid == 0) lcount = 0u;
    }

    const float*  p  = pop + (size_t)path * (LENN * 2);
    const float4* p4 = (const float4*)p;

    // Thread t owns points [4t, 4t+4): two float4 loads.
    float4 a = p4[tid * 2];
    float4 b = p4[tid * 2 + 1];
    float xs[5], ys[5];
    xs[0] = a.x; ys[0] = a.y;
    xs[1] = a.z; ys[1] = a.w;
    xs[2] = b.x; ys[2] = b.y;
    xs[3] = b.z; ys[3] = b.w;

    // Seam point (base+4): neighbor lane's first point via shuffle; lane 63
    // of each wave crosses a wave boundary -> do the 8B load (8 loads/block).
    const int base = tid * 4;
    {
        float nx = __shfl_down(xs[0], 1, 64);
        float ny = __shfl_down(ys[0], 1, 64);
        if ((tid & 63) == 63 && base + 4 < LENN) {
            float2 c = ((const float2*)p)[base + 4];
            nx = c.x; ny = c.y;
        }
        xs[4] = nx; ys[4] = ny;
    }
    const int nsteps = (base + 4 < LENN) ? 4 : 3;

    int code[4];
    #pragma unroll
    for (int j = 0; j < 4; ++j)
        code[j] = (int)xs[j] * GRIDN + (int)ys[j];

    // 4 independent random gathers into the L2-resident 1MB table.
    // (R3: nt -> L2 bypass, 2x worse. R4: sc0 L1-bypass, identical. Plain wins on simplicity.)
    float g[4];
    #pragma unroll
    for (int j = 0; j < 4; ++j) g[j] = tp[code[j]];

    __syncthreads();                 // bitmap zeroed (gathers already in flight)

    #pragma unroll
    for (int j = 0; j < 4; ++j) {
        unsigned w   = (unsigned)code[j] >> 5;
        unsigned bit = 1u << (code[j] & 31);
        unsigned old = atomicOr(&seen[w], bit);
        if (old & bit) {                          // 2nd-or-later visit: append
            unsigned idx = atomicAdd(&lcount, 1u);
            if (idx < LCAP) list[idx] = (unsigned)code[j];
        }
    }

    int cont = 0;
    #pragma unroll
    for (int j = 0; j < 4; ++j) {
        if (j < nsteps) {
            float d = fabsf(xs[j + 1] - xs[j]) + fabsf(ys[j + 1] - ys[j]);
            if (d > 1.0f) cont++;
        }
    }

    float reward = (g[0] + g[1]) + (g[2] + g[3]);

    __syncthreads();                 // list + lcount complete

    // n_dup_positions = unique codes in list. k is tiny (~8) for this data.
    int k = (int)lcount; if (k > LCAP) k = LCAP;
    int dupc = 0;
    for (int i = tid; i < k; i += TPB) {
        unsigned c = list[i];
        bool first = true;
        for (int j = 0; j < i; ++j)
            if (list[j] == c) { first = false; break; }
        if (first) dupc++;
    }

    float fit = reward - 0.5f * (float)cont - 0.2f * (float)dupc;

    // Wave shuffle reduce; partials into seen[0..7] (dead after atomics barrier).
    #pragma unroll
    for (int off = 32; off > 0; off >>= 1)
        fit += __shfl_down(fit, off, 64);

    float* scratch = (float*)seen;
    if ((tid & 63) == 0) scratch[tid >> 6] = fit;
    __syncthreads();
    if (tid == 0) {
        float s = 0.0f;
        #pragma unroll
        for (int w2 = 0; w2 < TPB / 64; ++w2) s += scratch[w2];
        out[path] = s;
    }
}

extern "C" void kernel_launch(void* const* d_in, const int* in_sizes, int n_in,
                              void* d_out, int out_size, void* d_ws, size_t ws_size,
                              hipStream_t stream) {
    const float* pop = (const float*)d_in[0];   // [POP, LEN, 2] f32
    const float* tp  = (const float*)d_in[1];   // [GRID, GRID] f32
    float* out = (float*)d_out;                 // [POP] f32
    (void)in_sizes; (void)n_in; (void)out_size; (void)d_ws; (void)ws_size;

    fitness_kernel<<<POPN, TPB, 0, stream>>>(pop, tp, out);
}